// Round 4
// baseline (72.556 us; speedup 1.0000x reference)
//
#include <hip/hip_runtime.h>

typedef float v2f __attribute__((ext_vector_type(2)));

#define NN 4096
#define TTOT 8192

constexpr int S     = 32;                  // t per compute thread
constexpr int HALO  = 4;                   // 4 kernel-2 layers -> cone of 4
constexpr int ROWS  = 16;                  // n-rows per block
constexpr int COLS  = 512;                 // t-cols per block
constexpr int UNITS = (COLS + HALO + 3) / 4;  // 129 float4 units per row
constexpr int PITCHU = 138;                // LDS row pitch in float4 units

__device__ __forceinline__ float fexp2(float x) {
#if __has_builtin(__builtin_amdgcn_exp2f)
    return __builtin_amdgcn_exp2f(x);
#else
    return exp2f(x);
#endif
}
__device__ __forceinline__ float frcp(float x) {
#if __has_builtin(__builtin_amdgcn_rcpf)
    return __builtin_amdgcn_rcpf(x);
#else
    return 1.0f / x;
#endif
}
__device__ __forceinline__ v2f splat(float x) { v2f r = {x, x}; return r; }

// LDS swizzle: injective within a row (XOR touches only low 3 bits of unit),
// row-XOR + pitch chosen so both the 256B-run writes and the 9-unit strided
// reads land 2 lanes/bank (free).
__device__ __forceinline__ int swz(int r, int u) {
    return r * PITCHU + (u ^ ((u >> 3) & 7) ^ (r & 7));
}

__global__ __launch_bounds__(256, 4) void gdcn_kernel(
    const float* __restrict__ x,
    const float* __restrict__ start_w,
    const float* __restrict__ start_b,
    const float* __restrict__ filter_w,
    const float* __restrict__ filter_b,
    const float* __restrict__ gate_w,
    const float* __restrict__ gate_b,
    float* __restrict__ out)
{
    __shared__ float4 lds[ROWS * PITCHU];   // 16*138*16 = 35328 B

    const int tid = threadIdx.x;
    const int bn  = blockIdx.x & 255;       // 4096/16 = 256 n-blocks (fast dim)
    const int bt  = blockIdx.x >> 8;        // 8192/512 = 16 t-blocks
    const int n0  = bn * ROWS;
    const int t0  = bt * COLS;
    const bool last = (bt == (TTOT / COLS) - 1);

    // ---- load phase: 256B contiguous runs per 16-lane group ----
    {
        const int lr = tid >> 4;            // row 0..15
        const int lu = tid & 15;            // unit lane 0..15
        const float4* xrow =
            reinterpret_cast<const float4*>(x + (size_t)(n0 + lr) * TTOT + t0);
        #pragma unroll
        for (int k = 0; k < 9; ++k) {
            const int u = lu + 16 * k;
            if (u < UNITS) {                // k=8: only lane 0 (unit 128)
                float4 val;
                if (last && u == UNITS - 1) {
                    val.x = val.y = val.z = val.w = 0.0f;   // t >= 8192
                } else {
                    val = xrow[u];
                }
                lds[swz(lr, u)] = val;
            }
        }
    }
    __syncthreads();

    // ---- compute phase ----
    const int cr = tid & 15;                // row 0..15
    const int cj = tid >> 4;                // 32-t segment 0..15
    const bool edge = last && (cj == 15);   // holds t >= 8192 in halo slots

    float v[S + HALO];
    #pragma unroll
    for (int q = 0; q < 9; ++q) {
        float4 f4 = lds[swz(cr, cj * 8 + q)];
        v[4*q+0] = f4.x; v[4*q+1] = f4.y; v[4*q+2] = f4.z; v[4*q+3] = f4.w;
    }

    constexpr float LOG2E = 1.4426950408889634f;

    // start 1x1 conv
    {
        const float sw = start_w[0], sb = start_b[0];
        #pragma unroll
        for (int s = 0; s < S + HALO; ++s) v[s] = fmaf(v[s], sw, sb);
        if (edge) {
            #pragma unroll
            for (int s = S; s < S + HALO; ++s) v[s] = 0.0f;  // per-layer zero pad
        }
    }

    // 4 gated layers:
    // tanh(F)*sigmoid(G) = (ef-1) * rcp((ef+1)*(1+eg)), ef=2^(2*log2e*F), eg=2^(-log2e*G)
    #pragma unroll
    for (int i = 0; i < 4; ++i) {
        const float ff0 = filter_w[2*i]   * (2.0f * LOG2E);
        const float ff1 = filter_w[2*i+1] * (2.0f * LOG2E);
        const float ffb = filter_b[i]     * (2.0f * LOG2E);
        const float gg0 = -gate_w[2*i]    * LOG2E;
        const float gg1 = -gate_w[2*i+1]  * LOG2E;
        const float ggb = -gate_b[i]      * LOG2E;
        const int len = S + HALO - 1 - i;       // 35,34,33,32

        #pragma unroll
        for (int s = 0; s + 1 < len; s += 2) {
            v2f a = { v[s],   v[s+1] };
            v2f b = { v[s+1], v[s+2] };
            v2f tf = a * splat(ff0) + b * splat(ff1) + splat(ffb);
            v2f tg = a * splat(gg0) + b * splat(gg1) + splat(ggb);
            if (i == 0) {   // layer-0 input unbounded: keep den in normal range
                tf.x = fminf(tf.x, 60.0f); tf.y = fminf(tf.y, 60.0f);
                tg.x = fminf(tg.x, 60.0f); tg.y = fminf(tg.y, 60.0f);
            }
            v2f ef = { fexp2(tf.x), fexp2(tf.y) };
            v2f eg = { fexp2(tg.x), fexp2(tg.y) };
            v2f num = ef - splat(1.0f);
            v2f den = (ef + splat(1.0f)) * (eg + splat(1.0f));
            v2f r   = { frcp(den.x), frcp(den.y) };
            v2f res = num * r;
            v[s] = res.x; v[s+1] = res.y;
        }
        if (len & 1) {
            const int s = len - 1;
            float a = v[s], b = v[s + 1];
            float tf = fmaf(a, ff0, fmaf(b, ff1, ffb));
            float tg = fmaf(a, gg0, fmaf(b, gg1, ggb));
            if (i == 0) { tf = fminf(tf, 60.0f); tg = fminf(tg, 60.0f); }
            float ef = fexp2(tf), eg = fexp2(tg);
            v[s] = (ef - 1.0f) * frcp((ef + 1.0f) * (eg + 1.0f));
        }
        if (edge) {
            #pragma unroll
            for (int s = S; s < S + HALO; ++s) v[s] = 0.0f;
        }
    }

    // ---- store: out[t][n]; lanes cover 16 contiguous n x 4 t = 4 full 64B lines ----
    float* op = out + (size_t)(t0 + cj * S) * NN + n0 + cr;
    #pragma unroll
    for (int s = 0; s < S; ++s)
        op[(size_t)s * NN] = v[s];
}

extern "C" void kernel_launch(void* const* d_in, const int* in_sizes, int n_in,
                              void* d_out, int out_size, void* d_ws, size_t ws_size,
                              hipStream_t stream) {
    const float* x  = (const float*)d_in[0];
    const float* sw = (const float*)d_in[1];
    const float* sb = (const float*)d_in[2];
    const float* fw = (const float*)d_in[3];
    const float* fb = (const float*)d_in[4];
    const float* gw = (const float*)d_in[5];
    const float* gb = (const float*)d_in[6];
    float* out = (float*)d_out;

    dim3 grid((NN / ROWS) * (TTOT / COLS));   // 256 * 16 = 4096 blocks
    gdcn_kernel<<<grid, 256, 0, stream>>>(x, sw, sb, fw, fb, gw, gb, out);
}

// Round 5
// 68.063 us; speedup vs baseline: 1.0660x; 1.0660x over previous
//
#include <hip/hip_runtime.h>

typedef float v2f __attribute__((ext_vector_type(2)));

#define NN 4096
#define TTOT 8192

constexpr int S      = 32;                    // t per compute thread
constexpr int HALO   = 4;                     // 4 kernel-2 layers -> cone of 4
constexpr int ROWS   = 32;                    // n-rows per block
constexpr int COLS   = 256;                   // t-cols per block
constexpr int UNITS  = (COLS + HALO + 3) / 4; // 65 float4 units per row
constexpr int PITCHU = 65;                    // odd pitch -> even bank spread

__device__ __forceinline__ float fexp2(float x) {
#if __has_builtin(__builtin_amdgcn_exp2f)
    return __builtin_amdgcn_exp2f(x);
#else
    return exp2f(x);
#endif
}
__device__ __forceinline__ float frcp(float x) {
#if __has_builtin(__builtin_amdgcn_rcpf)
    return __builtin_amdgcn_rcpf(x);
#else
    return 1.0f / x;
#endif
}
__device__ __forceinline__ v2f splat(float x) { v2f r = {x, x}; return r; }

__global__ __launch_bounds__(256, 4) void gdcn_kernel(
    const float* __restrict__ x,
    const float* __restrict__ start_w,
    const float* __restrict__ start_b,
    const float* __restrict__ filter_w,
    const float* __restrict__ filter_b,
    const float* __restrict__ gate_w,
    const float* __restrict__ gate_b,
    float* __restrict__ out)
{
    __shared__ float4 lds[ROWS * PITCHU];     // 32*65*16 = 33280 B

    const int tid = threadIdx.x;
    const int bn  = blockIdx.x & 127;         // 4096/32 = 128 n-blocks (fast dim)
    const int bt  = blockIdx.x >> 7;          // 8192/256 = 32 t-blocks
    const int n0  = bn * ROWS;
    const int t0  = bt * COLS;
    const bool last = (bt == (TTOT / COLS) - 1);

    // ---- load: 8 lanes per row, contiguous 128B runs (TA-mergeable) ----
    {
        const int lr = tid >> 3;              // row 0..31
        const int lu = tid & 7;               // unit lane 0..7
        const float4* xrow =
            reinterpret_cast<const float4*>(x + (size_t)(n0 + lr) * TTOT + t0);
        #pragma unroll
        for (int k = 0; k < 9; ++k) {
            const int u = lu + 8 * k;
            if (u < UNITS) {                  // k=8: only lu==0 (unit 64)
                float4 val;
                if (last && u == UNITS - 1) {
                    val.x = val.y = val.z = val.w = 0.0f;   // t >= 8192
                } else {
                    val = xrow[u];
                }
                lds[lr * PITCHU + u] = val;   // bank group (lr+u)&7: even
            }
        }
    }
    __syncthreads();

    // ---- compute ----
    const int cr = tid & 31;                  // row 0..31
    const int cj = tid >> 5;                  // 32-t segment 0..7
    const bool edge = last && (cj == 7);      // halo slots hold t >= 8192

    float v[S + HALO];
    #pragma unroll
    for (int q = 0; q < 9; ++q) {             // bank group (cr+q)&7: even
        float4 f4 = lds[cr * PITCHU + cj * 8 + q];
        v[4*q+0] = f4.x; v[4*q+1] = f4.y; v[4*q+2] = f4.z; v[4*q+3] = f4.w;
    }

    constexpr float LOG2E = 1.4426950408889634f;

    // start 1x1 conv
    {
        const float sw = start_w[0], sb = start_b[0];
        #pragma unroll
        for (int s = 0; s < S + HALO; ++s) v[s] = fmaf(v[s], sw, sb);
        if (edge) {
            #pragma unroll
            for (int s = S; s < S + HALO; ++s) v[s] = 0.0f;  // per-layer zero pad
        }
    }

    // 4 gated layers:
    // tanh(F)*sigmoid(G) = (ef-1) * rcp((ef+1)*(1+eg)), ef=2^(2*log2e*F), eg=2^(-log2e*G)
    #pragma unroll
    for (int i = 0; i < 4; ++i) {
        const float ff0 = filter_w[2*i]   * (2.0f * LOG2E);
        const float ff1 = filter_w[2*i+1] * (2.0f * LOG2E);
        const float ffb = filter_b[i]     * (2.0f * LOG2E);
        const float gg0 = -gate_w[2*i]    * LOG2E;
        const float gg1 = -gate_w[2*i+1]  * LOG2E;
        const float ggb = -gate_b[i]      * LOG2E;
        const int len = S + HALO - 1 - i;     // 35,34,33,32

        #pragma unroll
        for (int s = 0; s + 1 < len; s += 2) {
            v2f a = { v[s],   v[s+1] };
            v2f b = { v[s+1], v[s+2] };
            v2f tf = a * splat(ff0) + b * splat(ff1) + splat(ffb);
            v2f tg = a * splat(gg0) + b * splat(gg1) + splat(ggb);
            if (i == 0) {   // layer-0 input unbounded: keep den in normal range
                tf.x = fminf(tf.x, 60.0f); tf.y = fminf(tf.y, 60.0f);
                tg.x = fminf(tg.x, 60.0f); tg.y = fminf(tg.y, 60.0f);
            }
            v2f ef = { fexp2(tf.x), fexp2(tf.y) };
            v2f eg = { fexp2(tg.x), fexp2(tg.y) };
            v2f num = ef - splat(1.0f);
            v2f den = (ef + splat(1.0f)) * (eg + splat(1.0f));
            v2f r   = { frcp(den.x), frcp(den.y) };
            v2f res = num * r;
            v[s] = res.x; v[s+1] = res.y;
        }
        if (len & 1) {
            const int s = len - 1;
            float a = v[s], b = v[s + 1];
            float tf = fmaf(a, ff0, fmaf(b, ff1, ffb));
            float tg = fmaf(a, gg0, fmaf(b, gg1, ggb));
            if (i == 0) { tf = fminf(tf, 60.0f); tg = fminf(tg, 60.0f); }
            float ef = fexp2(tf), eg = fexp2(tg);
            v[s] = (ef - 1.0f) * frcp((ef + 1.0f) * (eg + 1.0f));
        }
        if (edge) {
            #pragma unroll
            for (int s = S; s < S + HALO; ++s) v[s] = 0.0f;
        }
    }

    // ---- store: out[t][n]; 32 contiguous n per half-wave = full 64B lines ----
    float* op = out + (size_t)(t0 + cj * S) * NN + n0 + cr;
    #pragma unroll
    for (int s = 0; s < S; ++s)
        op[(size_t)s * NN] = v[s];
}

extern "C" void kernel_launch(void* const* d_in, const int* in_sizes, int n_in,
                              void* d_out, int out_size, void* d_ws, size_t ws_size,
                              hipStream_t stream) {
    const float* x  = (const float*)d_in[0];
    const float* sw = (const float*)d_in[1];
    const float* sb = (const float*)d_in[2];
    const float* fw = (const float*)d_in[3];
    const float* fb = (const float*)d_in[4];
    const float* gw = (const float*)d_in[5];
    const float* gb = (const float*)d_in[6];
    float* out = (float*)d_out;

    dim3 grid((NN / ROWS) * (TTOT / COLS));   // 128 * 32 = 4096 blocks
    gdcn_kernel<<<grid, 256, 0, stream>>>(x, sw, sb, fw, fb, gw, gb, out);
}